// Round 16
// baseline (274.211 us; speedup 1.0000x reference)
//
#include <hip/hip_runtime.h>

#define HEADS 4
#define NH    256
#define LEN   4096
#define NB    16
#define TT    1024
#define NSUB  4

typedef float     f32x4 __attribute__((ext_vector_type(4)));
typedef _Float16  f16x2 __attribute__((ext_vector_type(2)));
typedef _Float16  f16x8 __attribute__((ext_vector_type(8)));
typedef unsigned  u32x2 __attribute__((ext_vector_type(2)));
typedef unsigned  u32x4 __attribute__((ext_vector_type(4)));

__device__ __forceinline__ unsigned packh(float a, float b) {
    union { _Float16 h[2]; unsigned u; } z;
    z.h[0] = (_Float16)a; z.h[1] = (_Float16)b;
    return z.u;
}
__device__ __forceinline__ unsigned short h16u(float a) {
    union { _Float16 h; unsigned short u; } z;
    z.h = (_Float16)a; return z.u;
}
__device__ __forceinline__ float lo16(unsigned u) {
    return (float)__builtin_bit_cast(f16x2, u)[0];
}
__device__ __forceinline__ float hi16(unsigned u) {
    return (float)__builtin_bit_cast(f16x2, u)[1];
}
// DR bank swizzles (bits>=2 only: preserves b64/b128 alignment & contiguity)
__device__ __forceinline__ int swzB(int d) { return d ^ ((d & 0xF0) >> 2); }
__device__ __forceinline__ int swzC(int d) { return d ^ ((d & 0xE0) >> 3); }

// ---------------------------------------------------------------------------
// Weight table (verified R7): per (h,c,unit): Prev[y] = w_u[95-y], f16.
// ---------------------------------------------------------------------------
__global__ __launch_bounds__(64) void build_wgt_kernel(
    const float* __restrict__ kernels, unsigned short* __restrict__ wtab)
{
    const int h    = blockIdx.x;
    const int lane = threadIdx.x;

    float ssum[4] = {0.f, 0.f, 0.f, 0.f};
    #pragma unroll
    for (int q = 0; q < 3; ++q) {
        const int tap = lane + q * 64;
        const int i = tap >> 5;
        const int j = tap & 31;
        const float scale = (float)(1 << (5 - i));
        const float repf  = (float)(i == 0 ? 1 : (1 << (i - 1)));
        #pragma unroll
        for (int c = 0; c < 4; ++c) {
            const float kv = kernels[(((i * HEADS) + c) * NH + h) * 32 + j];
            const float v  = kv * scale;
            ssum[c] += v * v * repf;
        }
    }
    #pragma unroll
    for (int off = 32; off > 0; off >>= 1) {
        #pragma unroll
        for (int c = 0; c < 4; ++c) ssum[c] += __shfl_xor(ssum[c], off);
    }
    float inv[4];
    #pragma unroll
    for (int c = 0; c < 4; ++c) inv[c] = 1.0f / sqrtf(ssum[c]);

    for (int it = 0; it < 40; ++it) {
        const int idx = it * 64 + lane;
        const int c   = idx / 640;
        const int rem = idx - c * 640;
        const int u   = rem >> 7;
        const int y   = rem & 127;
        const int j   = 95 - y;
        const int J   = (u == 0) ? 64 : 32;
        float val = 0.f;
        if (j >= 0 && j < J) {
            int s, tp;
            if (u == 0) { s = (j < 32) ? 0 : 1; tp = j & 31; }
            else        { s = u + 1;            tp = j;      }
            val = kernels[((s * HEADS + c) * NH + h) * 32 + tp]
                  * (float)(1 << (5 - s)) * inv[c];
        }
        wtab[((h * 4 + c) * 5 + u) * 128 + y] = h16u(val);
    }
}

// ---------------------------------------------------------------------------
// MFMA conv kernel.  Grid (2 cpair, 256 h, 16 b), 4 waves.
// R15 base (verified 148us) +:
//  - AFF full frags hoisted to registers once (saves 36 b128/wave; +48 VGPR)
//  - DR epilogue XOR-swizzled per array (all writes+reads bank-dense)
// ---------------------------------------------------------------------------
#define AFB   0                 // 12 full frags * 1024B
#define HFB   12288             // 10 half frags * 512B (lanes 0..31 only)
#define ZPB   17408             // 512B zero block (lanes >=32 of half frags)
#define GBASE 17920
#define G1B   (GBASE + 0)
#define G2B   (GBASE + 4160)
#define G4B   (GBASE + 8256)
#define G8B   (GBASE + 12352)
#define G16B  (GBASE + 16448)   // ends at GBASE+20544 = 38464
#define SMBYTES 38464
// DR scratch: per wave 3 arrays * 256 dwords (3KB), overlays GBASE.

#define SWZ(BASE, OFF, SH, MSK) \
    ((char*)SM + (BASE) + ((OFF) ^ ((((OFF) >> (SH)) & (MSK)) << 4)))

// full frag read: head cc, full-index fi in [0,6)
#define AFF(CC, FI) \
    (*(const f16x8*)((char*)SM + AFB + ((CC) * 6 + (FI)) * 1024 + lane * 16))
// half frag read: head cc, high-index hi in [0,5); lanes>=32 hit zero block
#define AFH(CC, HI) \
    (*(const f16x8*)((char*)SM + hbase + (hmask & (((CC) * 5 + (HI)) * 512))))

#define MFMA16(acc, a, bb) \
    (acc) = __builtin_amdgcn_mfma_f32_16x16x32_f16((a), (bb), (acc), 0, 0, 0)

__global__ __launch_bounds__(256, 4) void conv_kernel(
    const float*           __restrict__ x,
    const unsigned short*  __restrict__ wtab,
    const float*           __restrict__ Dp,
    float*                 __restrict__ out)
{
    __shared__ __align__(16) unsigned char SM[SMBYTES];

    const int cpair = blockIdx.x;
    const int h     = blockIdx.y;
    const int b     = blockIdx.z;
    const int tid   = threadIdx.x;
    const int w     = tid >> 6;
    const int lane  = tid & 63;
    const int dd    = lane & 15;
    const int qq    = lane >> 4;

    unsigned* DRW = (unsigned*)(SM + GBASE + w * 3072);   // 3*256 dwords/wave

    const float* xrow = x + ((size_t)(b * NH + h)) * LEN;

    // ---- AF build (wave 0): full frags 1KB, tail frags compact 512B ----
    if (w == 0) {
        #pragma unroll
        for (int cc = 0; cc < 2; ++cc) {
            const int c = cpair * 2 + cc;
            const unsigned short* wpc = wtab + (size_t)((h * 4 + c) * 5) * 128;
            #pragma unroll
            for (int u = 0; u < 5; ++u) {
                const int J  = (u == 0) ? 64 : 32;
                const int nM = (u == 0) ? 3 : 2;
                const unsigned short* wp = wpc + u * 128;
                #pragma unroll
                for (int m = 0; m < 3; ++m) {
                    if (m < nM) {
                        const int y0 = 95 - dd - J + 32 * m + 8 * qq;
                        u32x4 dw;
                        #pragma unroll
                        for (int d = 0; d < 4; ++d)
                            dw[d] = (unsigned)wp[y0 + 2 * d]
                                  | ((unsigned)wp[y0 + 2 * d + 1] << 16);
                        if (m == nM - 1) {       // tail frag: qq>=2 provably 0
                            if (lane < 32)
                                *(u32x4*)((char*)SM + HFB
                                    + (cc * 5 + u) * 512 + lane * 16) = dw;
                        } else {
                            const int fi = (u == 0) ? m : u + 1;
                            *(u32x4*)((char*)SM + AFB
                                + (cc * 6 + fi) * 1024 + lane * 16) = dw;
                        }
                    }
                }
            }
        }
    }
    if (tid < 32) *(u32x4*)((char*)SM + ZPB + tid * 16) = (u32x4){0, 0, 0, 0};
    __syncthreads();   // AF visible to all waves before hoist

    // ---- hoist the 12 full fragments into registers (loop-invariant) ----
    f16x8 AR[2][6];
    #pragma unroll
    for (int cc = 0; cc < 2; ++cc)
        #pragma unroll
        for (int fi = 0; fi < 6; ++fi) AR[cc][fi] = AFF(cc, fi);

    const float dC0 = Dp[(cpair * 2 + 0) * NH + h];
    const float dC1 = Dp[(cpair * 2 + 1) * NH + h];

    // half-frag addressing (masked base; lanes>=32 -> zero block)
    const int hbase = (lane < 32) ? (HFB + lane * 16) : (ZPB + (lane - 32) * 16);
    const int hmask = (lane < 32) ? ~0 : 0;

    // ---- B-fragment base BYTE offsets (array-local) per unit ----
    const int kap = 16 * w + dd;
    const int E0B = 32 * kap + 1920 + 16 * qq;
    const int E1B = 2048 * (kap & 1)  + 32 * (kap >> 1) + 896 + 16 * qq;
    const int E2B = 1024 * (kap & 3)  + 32 * (kap >> 2) + 384 + 16 * qq;
    const int E3B = 512  * (kap & 7)  + 32 * (kap >> 3) + 128 + 16 * qq;
    const int E4B = 256  * (kap & 15) + 32 * (kap >> 4)       + 16 * qq;

    // DR write/read dword bases (bijective lane->t maps)
    const int wB = 64 * qq + 4 * dd;                          // unit2 map
    const int wC = 128 * (qq >> 1) + 8 * dd + 4 * (qq & 1);   // unit3 map
    const int wD = 64 * qq + 2 * dd;                          // unit1 map
    const int rA = 16 * dd + 4 * qq;                          // MAP_A

    for (int st = 0; st < NSUB; ++st) {
        const int t0s = st * TT;
        __syncthreads();   // G rewrite vs prior-subtile DR reads

        // ---- prefix chain (register doubling) + swizzled f16 G-writes ----
        {
            const int bg = t0s - 544 + 8 * tid;
            float v[40];
            #pragma unroll
            for (int blk = 0; blk < 10; ++blk) {
                const int g = bg + 4 * blk;
                f32x4 t;
                if (g >= 0 && g + 3 < LEN) {
                    t = *(const f32x4*)(xrow + g);
                } else {
                    #pragma unroll
                    for (int e = 0; e < 4; ++e) {
                        const int gg = g + e;
                        t[e] = (gg >= 0 && gg < LEN) ? xrow[gg] : 0.f;
                    }
                }
                v[4 * blk] = t.x; v[4 * blk + 1] = t.y;
                v[4 * blk + 2] = t.z; v[4 * blk + 3] = t.w;
            }
            {   // G1 = x (f16)
                u32x4 px;
                px[0] = packh(v[32], v[33]); px[1] = packh(v[34], v[35]);
                px[2] = packh(v[36], v[37]); px[3] = packh(v[38], v[39]);
                *(u32x4*)SWZ(G1B, 16 * tid, 7, 1) = px;
            }
            // G1 tail pad (rewritten every subtile: DR overlay clobbers it)
            if (tid < 4)
                *(u32x4*)SWZ(G1B, 4096 + 16 * tid, 7, 1) = (u32x4){0, 0, 0, 0};

            #pragma unroll
            for (int j = 39; j >= 2; --j) v[j] += v[j - 1];      // W2
            #pragma unroll
            for (int ph = 0; ph < 2; ++ph) {
                u32x2 pw;
                pw.x = packh(v[32 + ph], v[34 + ph]);
                pw.y = packh(v[36 + ph], v[38 + ph]);
                *(u32x2*)SWZ(G2B, 2048 * ph + 8 * tid, 7, 1) = pw;
            }
            #pragma unroll
            for (int j = 39; j >= 4; --j) v[j] += v[j - 2];      // W4
            #pragma unroll
            for (int ph = 0; ph < 4; ++ph)
                *(unsigned*)SWZ(G4B, 1024 * ph + 4 * tid, 10, 1) =
                    packh(v[32 + ph], v[36 + ph]);
            #pragma unroll
            for (int j = 39; j >= 8; --j) v[j] += v[j - 4];      // W8
            #pragma unroll
            for (int e = 0; e < 8; ++e)
                *(unsigned short*)SWZ(G8B, 512 * e + 2 * tid, 9, 7) =
                    h16u(v[32 + e]);
            #pragma unroll
            for (int j = 39; j >= 16; --j) v[j] += v[j - 8];     // W16
            #pragma unroll
            for (int e = 0; e < 8; ++e) {
                const int E = 8 * (tid & 1) + e;
                *(unsigned short*)SWZ(G16B, 256 * E + 2 * (tid >> 1), 8, 7) =
                    h16u(v[32 + e]);
            }
        }
        __syncthreads();

        // ---- MFMA phase (units 1-4 operand-swapped; A full-frags in regs) --
        f32x4 DA_A[2], DA_B[2], DA_C[2], DA_D[2];
        #pragma unroll
        for (int cc = 0; cc < 2; ++cc) {
            DA_A[cc] = (f32x4){0.f, 0.f, 0.f, 0.f};
            DA_B[cc] = (f32x4){0.f, 0.f, 0.f, 0.f};
            DA_C[cc] = (f32x4){0.f, 0.f, 0.f, 0.f};
            DA_D[cc] = (f32x4){0.f, 0.f, 0.f, 0.f};
        }

        {   // unit 0 (r=1, K=96) NORMAL -> MAP_A
            const f16x8 b0 = *(const f16x8*)SWZ(G1B, E0B,       7, 1);
            const f16x8 b1 = *(const f16x8*)SWZ(G1B, E0B + 64,  7, 1);
            const f16x8 b2 = *(const f16x8*)SWZ(G1B, E0B + 128, 7, 1);
            #pragma unroll
            for (int cc = 0; cc < 2; ++cc) {
                MFMA16(DA_A[cc], AR[cc][0], b0);
                MFMA16(DA_A[cc], AR[cc][1], b1);
                MFMA16(DA_A[cc], AFH(cc, 0), b2);
            }
        }
        {   // unit 1 (r=2) SWAPPED -> DA_D
            const f16x8 b0 = *(const f16x8*)SWZ(G2B, E1B,      7, 1);
            const f16x8 b1 = *(const f16x8*)SWZ(G2B, E1B + 64, 7, 1);
            #pragma unroll
            for (int cc = 0; cc < 2; ++cc) {
                MFMA16(DA_D[cc], b0, AR[cc][2]);
                MFMA16(DA_D[cc], b1, AFH(cc, 1));
            }
        }
        {   // unit 2 (r=4) SWAPPED -> DA_B
            const f16x8 b0 = *(const f16x8*)SWZ(G4B, E2B,      10, 1);
            const f16x8 b1 = *(const f16x8*)SWZ(G4B, E2B + 64, 10, 1);
            #pragma unroll
            for (int cc = 0; cc < 2; ++cc) {
                MFMA16(DA_B[cc], b0, AR[cc][3]);
                MFMA16(DA_B[cc], b1, AFH(cc, 2));
            }
        }
        {   // unit 3 (r=8) SWAPPED -> DA_C
            const f16x8 b0 = *(const f16x8*)SWZ(G8B, E3B,      9, 7);
            const f16x8 b1 = *(const f16x8*)SWZ(G8B, E3B + 64, 9, 7);
            #pragma unroll
            for (int cc = 0; cc < 2; ++cc) {
                MFMA16(DA_C[cc], b0, AR[cc][4]);
                MFMA16(DA_C[cc], b1, AFH(cc, 3));
            }
        }
        {   // unit 4 (r=16) SWAPPED -> MAP_A, shares DA_A
            const f16x8 b0 = *(const f16x8*)SWZ(G16B, E4B,      8, 7);
            const f16x8 b1 = *(const f16x8*)SWZ(G16B, E4B + 64, 8, 7);
            #pragma unroll
            for (int cc = 0; cc < 2; ++cc) {
                MFMA16(DA_A[cc], b0, AR[cc][5]);
                MFMA16(DA_A[cc], b1, AFH(cc, 4));
            }
        }
        __syncthreads();   // all B-reads done; G region becomes DR scratch

        // ---- epilogue: swizzled t-indexed DR (bank-dense on every access) --
        {   // writes
            u32x4 pB, pC;
            u32x2 pD0, pD1;
            #pragma unroll
            for (int e = 0; e < 4; ++e) {
                pB[e] = packh(DA_B[0][e], DA_B[1][e]);
                pC[e] = packh(DA_C[0][e], DA_C[1][e]);
            }
            pD0.x = packh(DA_D[0][0], DA_D[1][0]);
            pD0.y = packh(DA_D[0][1], DA_D[1][1]);
            pD1.x = packh(DA_D[0][2], DA_D[1][2]);
            pD1.y = packh(DA_D[0][3], DA_D[1][3]);
            *(u32x4*)&DRW[swzB(wB)]              = pB;   // unit2, b128
            *(u32x4*)&DRW[256 + swzC(wC)]        = pC;   // unit3, b128
            *(u32x2*)&DRW[512 + swzB(wD)]        = pD0;  // unit1 lo, b64
            *(u32x2*)&DRW[512 + swzB(wD + 32)]   = pD1;  // unit1 hi, b64
        }
        const u32x4 qB = *(const u32x4*)&DRW[swzB(rA)];
        const u32x4 qC = *(const u32x4*)&DRW[256 + swzC(rA)];
        const u32x4 qD = *(const u32x4*)&DRW[512 + swzB(rA)];

        // ---- combine + skip + store at MAP_A ----
        const int gt = t0s + 256 * w + rA;
        const f32x4 xv = *(const f32x4*)(xrow + gt);
        const size_t ob = ((size_t)(b * NH + h) * 4 + cpair * 2) * LEN + gt;

        f32x4 a0, a1;
        #pragma unroll
        for (int e = 0; e < 4; ++e) {
            a0[e] = DA_A[0][e] + lo16(qB[e]) + lo16(qC[e]) + lo16(qD[e]);
            a1[e] = DA_A[1][e] + hi16(qB[e]) + hi16(qC[e]) + hi16(qD[e]);
        }
        *(f32x4*)(out + ob)       = a0 + xv * dC0;
        *(f32x4*)(out + ob + LEN) = a1 + xv * dC1;
    }
}

extern "C" void kernel_launch(void* const* d_in, const int* in_sizes, int n_in,
                              void* d_out, int out_size, void* d_ws, size_t ws_size,
                              hipStream_t stream)
{
    const float* x       = (const float*)d_in[0];
    const float* kernels = (const float*)d_in[1];
    const float* D       = (const float*)d_in[2];
    float*       out     = (float*)d_out;
    unsigned short* wtab = (unsigned short*)d_ws;   // 1.31 MB

    build_wgt_kernel<<<256, 64, 0, stream>>>(kernels, wtab);
    conv_kernel<<<dim3(2, NH, NB), 256, 0, stream>>>(x, wtab, D, out);
}

// Round 17
// 165.351 us; speedup vs baseline: 1.6584x; 1.6584x over previous
//
#include <hip/hip_runtime.h>

#define HEADS 4
#define NH    256
#define LEN   4096
#define NB    16
#define TT    1024
#define NSUB  4

typedef float     f32x4 __attribute__((ext_vector_type(4)));
typedef _Float16  f16x2 __attribute__((ext_vector_type(2)));
typedef _Float16  f16x8 __attribute__((ext_vector_type(8)));
typedef unsigned  u32x2 __attribute__((ext_vector_type(2)));
typedef unsigned  u32x4 __attribute__((ext_vector_type(4)));

__device__ __forceinline__ unsigned packh(float a, float b) {
    union { _Float16 h[2]; unsigned u; } z;
    z.h[0] = (_Float16)a; z.h[1] = (_Float16)b;
    return z.u;
}
__device__ __forceinline__ unsigned short h16u(float a) {
    union { _Float16 h; unsigned short u; } z;
    z.h = (_Float16)a; return z.u;
}
__device__ __forceinline__ float lo16(unsigned u) {
    return (float)__builtin_bit_cast(f16x2, u)[0];
}
__device__ __forceinline__ float hi16(unsigned u) {
    return (float)__builtin_bit_cast(f16x2, u)[1];
}
// DR bank swizzles (bits>=2 only: preserves b64/b128 alignment & contiguity)
__device__ __forceinline__ int swzB(int d) { return d ^ ((d & 0xF0) >> 2); }
__device__ __forceinline__ int swzC(int d) { return d ^ ((d & 0xE0) >> 3); }

// ---------------------------------------------------------------------------
// Weight table (verified R7): per (h,c,unit): Prev[y] = w_u[95-y], f16.
// ---------------------------------------------------------------------------
__global__ __launch_bounds__(64) void build_wgt_kernel(
    const float* __restrict__ kernels, unsigned short* __restrict__ wtab)
{
    const int h    = blockIdx.x;
    const int lane = threadIdx.x;

    float ssum[4] = {0.f, 0.f, 0.f, 0.f};
    #pragma unroll
    for (int q = 0; q < 3; ++q) {
        const int tap = lane + q * 64;
        const int i = tap >> 5;
        const int j = tap & 31;
        const float scale = (float)(1 << (5 - i));
        const float repf  = (float)(i == 0 ? 1 : (1 << (i - 1)));
        #pragma unroll
        for (int c = 0; c < 4; ++c) {
            const float kv = kernels[(((i * HEADS) + c) * NH + h) * 32 + j];
            const float v  = kv * scale;
            ssum[c] += v * v * repf;
        }
    }
    #pragma unroll
    for (int off = 32; off > 0; off >>= 1) {
        #pragma unroll
        for (int c = 0; c < 4; ++c) ssum[c] += __shfl_xor(ssum[c], off);
    }
    float inv[4];
    #pragma unroll
    for (int c = 0; c < 4; ++c) inv[c] = 1.0f / sqrtf(ssum[c]);

    for (int it = 0; it < 40; ++it) {
        const int idx = it * 64 + lane;
        const int c   = idx / 640;
        const int rem = idx - c * 640;
        const int u   = rem >> 7;
        const int y   = rem & 127;
        const int j   = 95 - y;
        const int J   = (u == 0) ? 64 : 32;
        float val = 0.f;
        if (j >= 0 && j < J) {
            int s, tp;
            if (u == 0) { s = (j < 32) ? 0 : 1; tp = j & 31; }
            else        { s = u + 1;            tp = j;      }
            val = kernels[((s * HEADS + c) * NH + h) * 32 + tp]
                  * (float)(1 << (5 - s)) * inv[c];
        }
        wtab[((h * 4 + c) * 5 + u) * 128 + y] = h16u(val);
    }
}

// ---------------------------------------------------------------------------
// MFMA conv kernel.  Grid (2 cpair, 256 h, 16 b), 4 waves.
// R15 base (verified 148us) + DR XOR-swizzle + AR hoist, now with
// __launch_bounds__(256,3): VGPR cap ~170 so the 48-reg AR hoist ALLOCATES
// (R16's (256,4) cap=128 made it spill: FETCH 70->400MB).  Expected alloc
// ~112-120 <=128 keeps 4 waves/SIMD in hardware.
// ---------------------------------------------------------------------------
#define AFB   0                 // 12 full frags * 1024B
#define HFB   12288             // 10 half frags * 512B (lanes 0..31 only)
#define ZPB   17408             // 512B zero block (lanes >=32 of half frags)
#define GBASE 17920
#define G1B   (GBASE + 0)
#define G2B   (GBASE + 4160)
#define G4B   (GBASE + 8256)
#define G8B   (GBASE + 12352)
#define G16B  (GBASE + 16448)   // ends at GBASE+20544 = 38464
#define SMBYTES 38464
// DR scratch: per wave 3 arrays * 256 dwords (3KB), overlays GBASE.

#define SWZ(BASE, OFF, SH, MSK) \
    ((char*)SM + (BASE) + ((OFF) ^ ((((OFF) >> (SH)) & (MSK)) << 4)))

// full frag read: head cc, full-index fi in [0,6)
#define AFF(CC, FI) \
    (*(const f16x8*)((char*)SM + AFB + ((CC) * 6 + (FI)) * 1024 + lane * 16))
// half frag read: head cc, high-index hi in [0,5); lanes>=32 hit zero block
#define AFH(CC, HI) \
    (*(const f16x8*)((char*)SM + hbase + (hmask & (((CC) * 5 + (HI)) * 512))))

#define MFMA16(acc, a, bb) \
    (acc) = __builtin_amdgcn_mfma_f32_16x16x32_f16((a), (bb), (acc), 0, 0, 0)

__global__ __launch_bounds__(256, 3) void conv_kernel(
    const float*           __restrict__ x,
    const unsigned short*  __restrict__ wtab,
    const float*           __restrict__ Dp,
    float*                 __restrict__ out)
{
    __shared__ __align__(16) unsigned char SM[SMBYTES];

    const int cpair = blockIdx.x;
    const int h     = blockIdx.y;
    const int b     = blockIdx.z;
    const int tid   = threadIdx.x;
    const int w     = tid >> 6;
    const int lane  = tid & 63;
    const int dd    = lane & 15;
    const int qq    = lane >> 4;

    unsigned* DRW = (unsigned*)(SM + GBASE + w * 3072);   // 3*256 dwords/wave

    const float* xrow = x + ((size_t)(b * NH + h)) * LEN;

    // ---- AF build (wave 0): full frags 1KB, tail frags compact 512B ----
    if (w == 0) {
        #pragma unroll
        for (int cc = 0; cc < 2; ++cc) {
            const int c = cpair * 2 + cc;
            const unsigned short* wpc = wtab + (size_t)((h * 4 + c) * 5) * 128;
            #pragma unroll
            for (int u = 0; u < 5; ++u) {
                const int J  = (u == 0) ? 64 : 32;
                const int nM = (u == 0) ? 3 : 2;
                const unsigned short* wp = wpc + u * 128;
                #pragma unroll
                for (int m = 0; m < 3; ++m) {
                    if (m < nM) {
                        const int y0 = 95 - dd - J + 32 * m + 8 * qq;
                        u32x4 dw;
                        #pragma unroll
                        for (int d = 0; d < 4; ++d)
                            dw[d] = (unsigned)wp[y0 + 2 * d]
                                  | ((unsigned)wp[y0 + 2 * d + 1] << 16);
                        if (m == nM - 1) {       // tail frag: qq>=2 provably 0
                            if (lane < 32)
                                *(u32x4*)((char*)SM + HFB
                                    + (cc * 5 + u) * 512 + lane * 16) = dw;
                        } else {
                            const int fi = (u == 0) ? m : u + 1;
                            *(u32x4*)((char*)SM + AFB
                                + (cc * 6 + fi) * 1024 + lane * 16) = dw;
                        }
                    }
                }
            }
        }
    }
    if (tid < 32) *(u32x4*)((char*)SM + ZPB + tid * 16) = (u32x4){0, 0, 0, 0};
    __syncthreads();   // AF visible to all waves before hoist

    // ---- hoist the 12 full fragments into registers (loop-invariant) ----
    f16x8 AR[2][6];
    #pragma unroll
    for (int cc = 0; cc < 2; ++cc)
        #pragma unroll
        for (int fi = 0; fi < 6; ++fi) AR[cc][fi] = AFF(cc, fi);

    const float dC0 = Dp[(cpair * 2 + 0) * NH + h];
    const float dC1 = Dp[(cpair * 2 + 1) * NH + h];

    // half-frag addressing (masked base; lanes>=32 -> zero block)
    const int hbase = (lane < 32) ? (HFB + lane * 16) : (ZPB + (lane - 32) * 16);
    const int hmask = (lane < 32) ? ~0 : 0;

    // ---- B-fragment base BYTE offsets (array-local) per unit ----
    const int kap = 16 * w + dd;
    const int E0B = 32 * kap + 1920 + 16 * qq;
    const int E1B = 2048 * (kap & 1)  + 32 * (kap >> 1) + 896 + 16 * qq;
    const int E2B = 1024 * (kap & 3)  + 32 * (kap >> 2) + 384 + 16 * qq;
    const int E3B = 512  * (kap & 7)  + 32 * (kap >> 3) + 128 + 16 * qq;
    const int E4B = 256  * (kap & 15) + 32 * (kap >> 4)       + 16 * qq;

    // DR write/read dword bases (bijective lane->t maps)
    const int wB = 64 * qq + 4 * dd;                          // unit2 map
    const int wC = 128 * (qq >> 1) + 8 * dd + 4 * (qq & 1);   // unit3 map
    const int wD = 64 * qq + 2 * dd;                          // unit1 map
    const int rA = 16 * dd + 4 * qq;                          // MAP_A

    for (int st = 0; st < NSUB; ++st) {
        const int t0s = st * TT;
        __syncthreads();   // G rewrite vs prior-subtile DR reads

        // ---- prefix chain (register doubling) + swizzled f16 G-writes ----
        {
            const int bg = t0s - 544 + 8 * tid;
            float v[40];
            #pragma unroll
            for (int blk = 0; blk < 10; ++blk) {
                const int g = bg + 4 * blk;
                f32x4 t;
                if (g >= 0 && g + 3 < LEN) {
                    t = *(const f32x4*)(xrow + g);
                } else {
                    #pragma unroll
                    for (int e = 0; e < 4; ++e) {
                        const int gg = g + e;
                        t[e] = (gg >= 0 && gg < LEN) ? xrow[gg] : 0.f;
                    }
                }
                v[4 * blk] = t.x; v[4 * blk + 1] = t.y;
                v[4 * blk + 2] = t.z; v[4 * blk + 3] = t.w;
            }
            {   // G1 = x (f16)
                u32x4 px;
                px[0] = packh(v[32], v[33]); px[1] = packh(v[34], v[35]);
                px[2] = packh(v[36], v[37]); px[3] = packh(v[38], v[39]);
                *(u32x4*)SWZ(G1B, 16 * tid, 7, 1) = px;
            }
            // G1 tail pad (rewritten every subtile: DR overlay clobbers it)
            if (tid < 4)
                *(u32x4*)SWZ(G1B, 4096 + 16 * tid, 7, 1) = (u32x4){0, 0, 0, 0};

            #pragma unroll
            for (int j = 39; j >= 2; --j) v[j] += v[j - 1];      // W2
            #pragma unroll
            for (int ph = 0; ph < 2; ++ph) {
                u32x2 pw;
                pw.x = packh(v[32 + ph], v[34 + ph]);
                pw.y = packh(v[36 + ph], v[38 + ph]);
                *(u32x2*)SWZ(G2B, 2048 * ph + 8 * tid, 7, 1) = pw;
            }
            #pragma unroll
            for (int j = 39; j >= 4; --j) v[j] += v[j - 2];      // W4
            #pragma unroll
            for (int ph = 0; ph < 4; ++ph)
                *(unsigned*)SWZ(G4B, 1024 * ph + 4 * tid, 10, 1) =
                    packh(v[32 + ph], v[36 + ph]);
            #pragma unroll
            for (int j = 39; j >= 8; --j) v[j] += v[j - 4];      // W8
            #pragma unroll
            for (int e = 0; e < 8; ++e)
                *(unsigned short*)SWZ(G8B, 512 * e + 2 * tid, 9, 7) =
                    h16u(v[32 + e]);
            #pragma unroll
            for (int j = 39; j >= 16; --j) v[j] += v[j - 8];     // W16
            #pragma unroll
            for (int e = 0; e < 8; ++e) {
                const int E = 8 * (tid & 1) + e;
                *(unsigned short*)SWZ(G16B, 256 * E + 2 * (tid >> 1), 8, 7) =
                    h16u(v[32 + e]);
            }
        }
        __syncthreads();

        // ---- MFMA phase (units 1-4 operand-swapped; A full-frags in regs) --
        f32x4 DA_A[2], DA_B[2], DA_C[2], DA_D[2];
        #pragma unroll
        for (int cc = 0; cc < 2; ++cc) {
            DA_A[cc] = (f32x4){0.f, 0.f, 0.f, 0.f};
            DA_B[cc] = (f32x4){0.f, 0.f, 0.f, 0.f};
            DA_C[cc] = (f32x4){0.f, 0.f, 0.f, 0.f};
            DA_D[cc] = (f32x4){0.f, 0.f, 0.f, 0.f};
        }

        {   // unit 0 (r=1, K=96) NORMAL -> MAP_A
            const f16x8 b0 = *(const f16x8*)SWZ(G1B, E0B,       7, 1);
            const f16x8 b1 = *(const f16x8*)SWZ(G1B, E0B + 64,  7, 1);
            const f16x8 b2 = *(const f16x8*)SWZ(G1B, E0B + 128, 7, 1);
            #pragma unroll
            for (int cc = 0; cc < 2; ++cc) {
                MFMA16(DA_A[cc], AR[cc][0], b0);
                MFMA16(DA_A[cc], AR[cc][1], b1);
                MFMA16(DA_A[cc], AFH(cc, 0), b2);
            }
        }
        {   // unit 1 (r=2) SWAPPED -> DA_D
            const f16x8 b0 = *(const f16x8*)SWZ(G2B, E1B,      7, 1);
            const f16x8 b1 = *(const f16x8*)SWZ(G2B, E1B + 64, 7, 1);
            #pragma unroll
            for (int cc = 0; cc < 2; ++cc) {
                MFMA16(DA_D[cc], b0, AR[cc][2]);
                MFMA16(DA_D[cc], b1, AFH(cc, 1));
            }
        }
        {   // unit 2 (r=4) SWAPPED -> DA_B
            const f16x8 b0 = *(const f16x8*)SWZ(G4B, E2B,      10, 1);
            const f16x8 b1 = *(const f16x8*)SWZ(G4B, E2B + 64, 10, 1);
            #pragma unroll
            for (int cc = 0; cc < 2; ++cc) {
                MFMA16(DA_B[cc], b0, AR[cc][3]);
                MFMA16(DA_B[cc], b1, AFH(cc, 2));
            }
        }
        {   // unit 3 (r=8) SWAPPED -> DA_C
            const f16x8 b0 = *(const f16x8*)SWZ(G8B, E3B,      9, 7);
            const f16x8 b1 = *(const f16x8*)SWZ(G8B, E3B + 64, 9, 7);
            #pragma unroll
            for (int cc = 0; cc < 2; ++cc) {
                MFMA16(DA_C[cc], b0, AR[cc][4]);
                MFMA16(DA_C[cc], b1, AFH(cc, 3));
            }
        }
        {   // unit 4 (r=16) SWAPPED -> MAP_A, shares DA_A
            const f16x8 b0 = *(const f16x8*)SWZ(G16B, E4B,      8, 7);
            const f16x8 b1 = *(const f16x8*)SWZ(G16B, E4B + 64, 8, 7);
            #pragma unroll
            for (int cc = 0; cc < 2; ++cc) {
                MFMA16(DA_A[cc], b0, AR[cc][5]);
                MFMA16(DA_A[cc], b1, AFH(cc, 4));
            }
        }
        __syncthreads();   // all B-reads done; G region becomes DR scratch

        // ---- epilogue: swizzled t-indexed DR (bank-dense on every access) --
        {   // writes
            u32x4 pB, pC;
            u32x2 pD0, pD1;
            #pragma unroll
            for (int e = 0; e < 4; ++e) {
                pB[e] = packh(DA_B[0][e], DA_B[1][e]);
                pC[e] = packh(DA_C[0][e], DA_C[1][e]);
            }
            pD0.x = packh(DA_D[0][0], DA_D[1][0]);
            pD0.y = packh(DA_D[0][1], DA_D[1][1]);
            pD1.x = packh(DA_D[0][2], DA_D[1][2]);
            pD1.y = packh(DA_D[0][3], DA_D[1][3]);
            *(u32x4*)&DRW[swzB(wB)]              = pB;   // unit2, b128
            *(u32x4*)&DRW[256 + swzC(wC)]        = pC;   // unit3, b128
            *(u32x2*)&DRW[512 + swzB(wD)]        = pD0;  // unit1 lo, b64
            *(u32x2*)&DRW[512 + swzB(wD + 32)]   = pD1;  // unit1 hi, b64
        }
        const u32x4 qB = *(const u32x4*)&DRW[swzB(rA)];
        const u32x4 qC = *(const u32x4*)&DRW[256 + swzC(rA)];
        const u32x4 qD = *(const u32x4*)&DRW[512 + swzB(rA)];

        // ---- combine + skip + store at MAP_A ----
        const int gt = t0s + 256 * w + rA;
        const f32x4 xv = *(const f32x4*)(xrow + gt);
        const size_t ob = ((size_t)(b * NH + h) * 4 + cpair * 2) * LEN + gt;

        f32x4 a0, a1;
        #pragma unroll
        for (int e = 0; e < 4; ++e) {
            a0[e] = DA_A[0][e] + lo16(qB[e]) + lo16(qC[e]) + lo16(qD[e]);
            a1[e] = DA_A[1][e] + hi16(qB[e]) + hi16(qC[e]) + hi16(qD[e]);
        }
        *(f32x4*)(out + ob)       = a0 + xv * dC0;
        *(f32x4*)(out + ob + LEN) = a1 + xv * dC1;
    }
}

extern "C" void kernel_launch(void* const* d_in, const int* in_sizes, int n_in,
                              void* d_out, int out_size, void* d_ws, size_t ws_size,
                              hipStream_t stream)
{
    const float* x       = (const float*)d_in[0];
    const float* kernels = (const float*)d_in[1];
    const float* D       = (const float*)d_in[2];
    float*       out     = (float*)d_out;
    unsigned short* wtab = (unsigned short*)d_ws;   // 1.31 MB

    build_wgt_kernel<<<256, 64, 0, stream>>>(kernels, wtab);
    conv_kernel<<<dim3(2, NH, NB), 256, 0, stream>>>(x, wtab, D, out);
}

// Round 18
// 145.919 us; speedup vs baseline: 1.8792x; 1.1332x over previous
//
#include <hip/hip_runtime.h>

#define HEADS 4
#define NH    256
#define LEN   4096
#define NB    16
#define TT    1024
#define NSUB  4

typedef float     f32x4 __attribute__((ext_vector_type(4)));
typedef _Float16  f16x2 __attribute__((ext_vector_type(2)));
typedef _Float16  f16x8 __attribute__((ext_vector_type(8)));
typedef unsigned  u32x2 __attribute__((ext_vector_type(2)));
typedef unsigned  u32x4 __attribute__((ext_vector_type(4)));

__device__ __forceinline__ unsigned packh(float a, float b) {
    union { _Float16 h[2]; unsigned u; } z;
    z.h[0] = (_Float16)a; z.h[1] = (_Float16)b;
    return z.u;
}
__device__ __forceinline__ unsigned short h16u(float a) {
    union { _Float16 h; unsigned short u; } z;
    z.h = (_Float16)a; return z.u;
}
__device__ __forceinline__ float lo16(unsigned u) {
    return (float)__builtin_bit_cast(f16x2, u)[0];
}
__device__ __forceinline__ float hi16(unsigned u) {
    return (float)__builtin_bit_cast(f16x2, u)[1];
}
// DR bank swizzles (bits>=2 only: preserves b64/b128 alignment & contiguity;
// verified correct R16/R17, conflicts 8.65e6 -> 7.08e6)
__device__ __forceinline__ int swzB(int d) { return d ^ ((d & 0xF0) >> 2); }
__device__ __forceinline__ int swzC(int d) { return d ^ ((d & 0xE0) >> 3); }

// ---------------------------------------------------------------------------
// Weight table (verified R7): per (h,c,unit): Prev[y] = w_u[95-y], f16.
// ---------------------------------------------------------------------------
__global__ __launch_bounds__(64) void build_wgt_kernel(
    const float* __restrict__ kernels, unsigned short* __restrict__ wtab)
{
    const int h    = blockIdx.x;
    const int lane = threadIdx.x;

    float ssum[4] = {0.f, 0.f, 0.f, 0.f};
    #pragma unroll
    for (int q = 0; q < 3; ++q) {
        const int tap = lane + q * 64;
        const int i = tap >> 5;
        const int j = tap & 31;
        const float scale = (float)(1 << (5 - i));
        const float repf  = (float)(i == 0 ? 1 : (1 << (i - 1)));
        #pragma unroll
        for (int c = 0; c < 4; ++c) {
            const float kv = kernels[(((i * HEADS) + c) * NH + h) * 32 + j];
            const float v  = kv * scale;
            ssum[c] += v * v * repf;
        }
    }
    #pragma unroll
    for (int off = 32; off > 0; off >>= 1) {
        #pragma unroll
        for (int c = 0; c < 4; ++c) ssum[c] += __shfl_xor(ssum[c], off);
    }
    float inv[4];
    #pragma unroll
    for (int c = 0; c < 4; ++c) inv[c] = 1.0f / sqrtf(ssum[c]);

    for (int it = 0; it < 40; ++it) {
        const int idx = it * 64 + lane;
        const int c   = idx / 640;
        const int rem = idx - c * 640;
        const int u   = rem >> 7;
        const int y   = rem & 127;
        const int j   = 95 - y;
        const int J   = (u == 0) ? 64 : 32;
        float val = 0.f;
        if (j >= 0 && j < J) {
            int s, tp;
            if (u == 0) { s = (j < 32) ? 0 : 1; tp = j & 31; }
            else        { s = u + 1;            tp = j;      }
            val = kernels[((s * HEADS + c) * NH + h) * 32 + tp]
                  * (float)(1 << (5 - s)) * inv[c];
        }
        wtab[((h * 4 + c) * 5 + u) * 128 + y] = h16u(val);
    }
}

// ---------------------------------------------------------------------------
// MFMA conv kernel.  Grid (2 cpair, 256 h, 16 b), 4 waves.
// R15 base (verified 148us, VGPR=64 -- MUST stay <=64: R16/R17 both showed
// crossing 64 VGPR costs more in residency than any LDS saving) +
//  - DR XOR-swizzle (swzB/swzC, verified R16/R17)
//  - DR overlay moved to G4/G8/G16 only -> G1 tail pad written once
// ---------------------------------------------------------------------------
#define AFB   0                 // 12 full frags * 1024B
#define HFB   12288             // 10 half frags * 512B (lanes 0..31 only)
#define ZPB   17408             // 512B zero block (lanes >=32 of half frags)
#define GBASE 17920
#define G1B   (GBASE + 0)
#define G2B   (GBASE + 4160)
#define G4B   (GBASE + 8256)
#define G8B   (GBASE + 12352)
#define G16B  (GBASE + 16448)   // ends at GBASE+20544 = 38464
#define DRB   (GBASE + 8256)    // DR 4 waves * 3072B = 12288 over G4/G8/G16
#define SMBYTES 38464

#define SWZ(BASE, OFF, SH, MSK) \
    ((char*)SM + (BASE) + ((OFF) ^ ((((OFF) >> (SH)) & (MSK)) << 4)))

// full frag read: head cc, full-index fi in [0,6)
#define AFF(CC, FI) \
    (*(const f16x8*)((char*)SM + AFB + ((CC) * 6 + (FI)) * 1024 + lane * 16))
// half frag read: head cc, high-index hi in [0,5); lanes>=32 hit zero block
#define AFH(CC, HI) \
    (*(const f16x8*)((char*)SM + hbase + (hmask & (((CC) * 5 + (HI)) * 512))))

#define MFMA16(acc, a, bb) \
    (acc) = __builtin_amdgcn_mfma_f32_16x16x32_f16((a), (bb), (acc), 0, 0, 0)

__global__ __launch_bounds__(256, 4) void conv_kernel(
    const float*           __restrict__ x,
    const unsigned short*  __restrict__ wtab,
    const float*           __restrict__ Dp,
    float*                 __restrict__ out)
{
    __shared__ __align__(16) unsigned char SM[SMBYTES];

    const int cpair = blockIdx.x;
    const int h     = blockIdx.y;
    const int b     = blockIdx.z;
    const int tid   = threadIdx.x;
    const int w     = tid >> 6;
    const int lane  = tid & 63;
    const int dd    = lane & 15;
    const int qq    = lane >> 4;

    unsigned* DRW = (unsigned*)(SM + DRB + w * 3072);   // 3*256 dwords/wave

    const float* xrow = x + ((size_t)(b * NH + h)) * LEN;

    // ---- AF build (wave 0): full frags 1KB, tail frags compact 512B ----
    if (w == 0) {
        #pragma unroll
        for (int cc = 0; cc < 2; ++cc) {
            const int c = cpair * 2 + cc;
            const unsigned short* wpc = wtab + (size_t)((h * 4 + c) * 5) * 128;
            #pragma unroll
            for (int u = 0; u < 5; ++u) {
                const int J  = (u == 0) ? 64 : 32;
                const int nM = (u == 0) ? 3 : 2;
                const unsigned short* wp = wpc + u * 128;
                #pragma unroll
                for (int m = 0; m < 3; ++m) {
                    if (m < nM) {
                        const int y0 = 95 - dd - J + 32 * m + 8 * qq;
                        u32x4 dw;
                        #pragma unroll
                        for (int d = 0; d < 4; ++d)
                            dw[d] = (unsigned)wp[y0 + 2 * d]
                                  | ((unsigned)wp[y0 + 2 * d + 1] << 16);
                        if (m == nM - 1) {       // tail frag: qq>=2 provably 0
                            if (lane < 32)
                                *(u32x4*)((char*)SM + HFB
                                    + (cc * 5 + u) * 512 + lane * 16) = dw;
                        } else {
                            const int fi = (u == 0) ? m : u + 1;
                            *(u32x4*)((char*)SM + AFB
                                + (cc * 6 + fi) * 1024 + lane * 16) = dw;
                        }
                    }
                }
            }
        }
    }
    if (tid < 32) *(u32x4*)((char*)SM + ZPB + tid * 16) = (u32x4){0, 0, 0, 0};
    // G1 tail pad zeros: written ONCE (DR no longer overlays G1)
    if (tid < 4)
        *(u32x4*)SWZ(G1B, 4096 + 16 * tid, 7, 1) = (u32x4){0, 0, 0, 0};

    const float dC0 = Dp[(cpair * 2 + 0) * NH + h];
    const float dC1 = Dp[(cpair * 2 + 1) * NH + h];

    // half-frag addressing (masked base; lanes>=32 -> zero block)
    const int hbase = (lane < 32) ? (HFB + lane * 16) : (ZPB + (lane - 32) * 16);
    const int hmask = (lane < 32) ? ~0 : 0;

    // ---- B-fragment base BYTE offsets (array-local) per unit ----
    const int kap = 16 * w + dd;
    const int E0B = 32 * kap + 1920 + 16 * qq;
    const int E1B = 2048 * (kap & 1)  + 32 * (kap >> 1) + 896 + 16 * qq;
    const int E2B = 1024 * (kap & 3)  + 32 * (kap >> 2) + 384 + 16 * qq;
    const int E3B = 512  * (kap & 7)  + 32 * (kap >> 3) + 128 + 16 * qq;
    const int E4B = 256  * (kap & 15) + 32 * (kap >> 4)       + 16 * qq;

    // DR write/read dword bases (bijective lane->t maps)
    const int wB = 64 * qq + 4 * dd;                          // unit2 map
    const int wC = 128 * (qq >> 1) + 8 * dd + 4 * (qq & 1);   // unit3 map
    const int wD = 64 * qq + 2 * dd;                          // unit1 map
    const int rA = 16 * dd + 4 * qq;                          // MAP_A

    for (int st = 0; st < NSUB; ++st) {
        const int t0s = st * TT;
        __syncthreads();   // G rewrite vs prior-subtile DR reads / AF ready

        // ---- prefix chain (register doubling) + swizzled f16 G-writes ----
        {
            const int bg = t0s - 544 + 8 * tid;
            float v[40];
            #pragma unroll
            for (int blk = 0; blk < 10; ++blk) {
                const int g = bg + 4 * blk;
                f32x4 t;
                if (g >= 0 && g + 3 < LEN) {
                    t = *(const f32x4*)(xrow + g);
                } else {
                    #pragma unroll
                    for (int e = 0; e < 4; ++e) {
                        const int gg = g + e;
                        t[e] = (gg >= 0 && gg < LEN) ? xrow[gg] : 0.f;
                    }
                }
                v[4 * blk] = t.x; v[4 * blk + 1] = t.y;
                v[4 * blk + 2] = t.z; v[4 * blk + 3] = t.w;
            }
            {   // G1 = x (f16)
                u32x4 px;
                px[0] = packh(v[32], v[33]); px[1] = packh(v[34], v[35]);
                px[2] = packh(v[36], v[37]); px[3] = packh(v[38], v[39]);
                *(u32x4*)SWZ(G1B, 16 * tid, 7, 1) = px;
            }
            #pragma unroll
            for (int j = 39; j >= 2; --j) v[j] += v[j - 1];      // W2
            #pragma unroll
            for (int ph = 0; ph < 2; ++ph) {
                u32x2 pw;
                pw.x = packh(v[32 + ph], v[34 + ph]);
                pw.y = packh(v[36 + ph], v[38 + ph]);
                *(u32x2*)SWZ(G2B, 2048 * ph + 8 * tid, 7, 1) = pw;
            }
            #pragma unroll
            for (int j = 39; j >= 4; --j) v[j] += v[j - 2];      // W4
            #pragma unroll
            for (int ph = 0; ph < 4; ++ph)
                *(unsigned*)SWZ(G4B, 1024 * ph + 4 * tid, 10, 1) =
                    packh(v[32 + ph], v[36 + ph]);
            #pragma unroll
            for (int j = 39; j >= 8; --j) v[j] += v[j - 4];      // W8
            #pragma unroll
            for (int e = 0; e < 8; ++e)
                *(unsigned short*)SWZ(G8B, 512 * e + 2 * tid, 9, 7) =
                    h16u(v[32 + e]);
            #pragma unroll
            for (int j = 39; j >= 16; --j) v[j] += v[j - 8];     // W16
            #pragma unroll
            for (int e = 0; e < 8; ++e) {
                const int E = 8 * (tid & 1) + e;
                *(unsigned short*)SWZ(G16B, 256 * E + 2 * (tid >> 1), 8, 7) =
                    h16u(v[32 + e]);
            }
        }
        __syncthreads();

        // ---- MFMA phase (units 1-4 operand-swapped) ----
        f32x4 DA_A[2], DA_B[2], DA_C[2], DA_D[2];
        #pragma unroll
        for (int cc = 0; cc < 2; ++cc) {
            DA_A[cc] = (f32x4){0.f, 0.f, 0.f, 0.f};
            DA_B[cc] = (f32x4){0.f, 0.f, 0.f, 0.f};
            DA_C[cc] = (f32x4){0.f, 0.f, 0.f, 0.f};
            DA_D[cc] = (f32x4){0.f, 0.f, 0.f, 0.f};
        }

        {   // unit 0 (r=1, K=96) NORMAL -> MAP_A
            const f16x8 b0 = *(const f16x8*)SWZ(G1B, E0B,       7, 1);
            const f16x8 b1 = *(const f16x8*)SWZ(G1B, E0B + 64,  7, 1);
            const f16x8 b2 = *(const f16x8*)SWZ(G1B, E0B + 128, 7, 1);
            #pragma unroll
            for (int cc = 0; cc < 2; ++cc) {
                MFMA16(DA_A[cc], AFF(cc, 0), b0);
                MFMA16(DA_A[cc], AFF(cc, 1), b1);
                MFMA16(DA_A[cc], AFH(cc, 0), b2);
            }
        }
        {   // unit 1 (r=2) SWAPPED -> DA_D
            const f16x8 b0 = *(const f16x8*)SWZ(G2B, E1B,      7, 1);
            const f16x8 b1 = *(const f16x8*)SWZ(G2B, E1B + 64, 7, 1);
            #pragma unroll
            for (int cc = 0; cc < 2; ++cc) {
                MFMA16(DA_D[cc], b0, AFF(cc, 2));
                MFMA16(DA_D[cc], b1, AFH(cc, 1));
            }
        }
        {   // unit 2 (r=4) SWAPPED -> DA_B
            const f16x8 b0 = *(const f16x8*)SWZ(G4B, E2B,      10, 1);
            const f16x8 b1 = *(const f16x8*)SWZ(G4B, E2B + 64, 10, 1);
            #pragma unroll
            for (int cc = 0; cc < 2; ++cc) {
                MFMA16(DA_B[cc], b0, AFF(cc, 3));
                MFMA16(DA_B[cc], b1, AFH(cc, 2));
            }
        }
        {   // unit 3 (r=8) SWAPPED -> DA_C
            const f16x8 b0 = *(const f16x8*)SWZ(G8B, E3B,      9, 7);
            const f16x8 b1 = *(const f16x8*)SWZ(G8B, E3B + 64, 9, 7);
            #pragma unroll
            for (int cc = 0; cc < 2; ++cc) {
                MFMA16(DA_C[cc], b0, AFF(cc, 4));
                MFMA16(DA_C[cc], b1, AFH(cc, 3));
            }
        }
        {   // unit 4 (r=16) SWAPPED -> MAP_A, shares DA_A
            const f16x8 b0 = *(const f16x8*)SWZ(G16B, E4B,      8, 7);
            const f16x8 b1 = *(const f16x8*)SWZ(G16B, E4B + 64, 8, 7);
            #pragma unroll
            for (int cc = 0; cc < 2; ++cc) {
                MFMA16(DA_A[cc], b0, AFF(cc, 5));
                MFMA16(DA_A[cc], b1, AFH(cc, 4));
            }
        }
        __syncthreads();   // all B-reads done; G4/G8/G16 become DR scratch

        // ---- epilogue: swizzled t-indexed DR (bank-dense on every access) --
        {   // writes
            u32x4 pB, pC;
            u32x2 pD0, pD1;
            #pragma unroll
            for (int e = 0; e < 4; ++e) {
                pB[e] = packh(DA_B[0][e], DA_B[1][e]);
                pC[e] = packh(DA_C[0][e], DA_C[1][e]);
            }
            pD0.x = packh(DA_D[0][0], DA_D[1][0]);
            pD0.y = packh(DA_D[0][1], DA_D[1][1]);
            pD1.x = packh(DA_D[0][2], DA_D[1][2]);
            pD1.y = packh(DA_D[0][3], DA_D[1][3]);
            *(u32x4*)&DRW[swzB(wB)]              = pB;   // unit2, b128
            *(u32x4*)&DRW[256 + swzC(wC)]        = pC;   // unit3, b128
            *(u32x2*)&DRW[512 + swzB(wD)]        = pD0;  // unit1 lo, b64
            *(u32x2*)&DRW[512 + swzB(wD + 32)]   = pD1;  // unit1 hi, b64
        }
        const u32x4 qB = *(const u32x4*)&DRW[swzB(rA)];
        const u32x4 qC = *(const u32x4*)&DRW[256 + swzC(rA)];
        const u32x4 qD = *(const u32x4*)&DRW[512 + swzB(rA)];

        // ---- combine + skip + store at MAP_A ----
        const int gt = t0s + 256 * w + rA;
        const f32x4 xv = *(const f32x4*)(xrow + gt);
        const size_t ob = ((size_t)(b * NH + h) * 4 + cpair * 2) * LEN + gt;

        f32x4 a0, a1;
        #pragma unroll
        for (int e = 0; e < 4; ++e) {
            a0[e] = DA_A[0][e] + lo16(qB[e]) + lo16(qC[e]) + lo16(qD[e]);
            a1[e] = DA_A[1][e] + hi16(qB[e]) + hi16(qC[e]) + hi16(qD[e]);
        }
        *(f32x4*)(out + ob)       = a0 + xv * dC0;
        *(f32x4*)(out + ob + LEN) = a1 + xv * dC1;
    }
}

extern "C" void kernel_launch(void* const* d_in, const int* in_sizes, int n_in,
                              void* d_out, int out_size, void* d_ws, size_t ws_size,
                              hipStream_t stream)
{
    const float* x       = (const float*)d_in[0];
    const float* kernels = (const float*)d_in[1];
    const float* D       = (const float*)d_in[2];
    float*       out     = (float*)d_out;
    unsigned short* wtab = (unsigned short*)d_ws;   // 1.31 MB

    build_wgt_kernel<<<256, 64, 0, stream>>>(kernels, wtab);
    conv_kernel<<<dim3(2, NH, NB), 256, 0, stream>>>(x, wtab, D, out);
}